// Round 4
// baseline (351.831 us; speedup 1.0000x reference)
//
#include <hip/hip_runtime.h>
#include <hip/hip_bf16.h>

#define NTOK 196
#define CDIM 768
#define BSAMP 256
#define TASKS 512
#define NCLS 701
#define NCLSP 704
#define NCHK 7      // chunks per task
#define CHTOK 28    // tokens per chunk (7 tokens per wave x 4 waves)

typedef __attribute__((ext_vector_type(8))) short bf16x8;
typedef __attribute__((ext_vector_type(4))) float f32x4;

__device__ __forceinline__ void add4(float4& a, const float4& b) {
  a.x += b.x; a.y += b.y; a.z += b.z; a.w += b.w;
}

// ---------------------------------------------------------------------------
// K1: streaming column-sum + energy kernel.
// R0/R2/R3 all pinned at 123us with 16 waves/CU (grid=512 -> 2 blocks/CU);
// per-CU read rate ~12 GB/s = exactly half of m13's 24.6 GB/s/CU at 32
// waves/CU. Throughput is linear in resident waves, so: 3584 blocks of 256
// threads -> 8 blocks/CU = 32 waves/CU. launch_bounds(256,8) caps VGPR at 64
// (est. use ~55, no spill); LDS 12KB.
// Each wave handles 7 tokens (t = chunk*28 + wv + 4*i) in pairs for ILP.
// Per-token energy uses the IDENTICAL lane mapping, add tree, and butterfly
// as the previous passing kernel -> M values bitwise identical -> Phase B's
// k / rank / subset selection unchanged. Column sums become 7 chunk-partials
// (fp32 workspace) combined in K2 -- grouping change only, tolerance-covered.
// ---------------------------------------------------------------------------
__global__ __launch_bounds__(256, 8) void colsum_kernel(const float* __restrict__ x1,
                                                        const float* __restrict__ x2,
                                                        float* __restrict__ colp,
                                                        float* __restrict__ Mg) {
  const int blk   = blockIdx.x;        // 0..3583
  const int task  = blk / NCHK;        // 0..511
  const int chunk = blk % NCHK;        // 0..6
  const int s  = task & 255;
  const int br = task >> 8;
  const float* __restrict__ feats = (br ? x2 : x1) + (size_t)s * (NTOK * CDIM);

  const int tid  = threadIdx.x;
  const int lane = tid & 63;
  const int wv   = tid >> 6;   // 0..3

  __shared__ float part[4][CDIM];   // 12 KB

  float4 acc[3];
  #pragma unroll
  for (int g = 0; g < 3; g++) acc[g] = make_float4(0.f, 0.f, 0.f, 0.f);

  const float* lanebase = feats + lane * 4;
  const int tbase = chunk * CHTOK;

  // 3 pairs + 1 tail = 7 tokens per wave; pairs give 6 loads in flight and
  // two independent butterfly chains.
  #pragma unroll 1
  for (int i = 0; i < 6; i += 2) {
    const int ta = tbase + wv + 4 * i;
    const int tb = ta + 4;
    const float* pa = lanebase + (size_t)ta * CDIM;
    const float* pb = lanebase + (size_t)tb * CDIM;
    float4 ra0 = *(const float4*)(pa);
    float4 ra1 = *(const float4*)(pa + 256);
    float4 ra2 = *(const float4*)(pa + 512);
    float4 rb0 = *(const float4*)(pb);
    float4 rb1 = *(const float4*)(pb + 256);
    float4 rb2 = *(const float4*)(pb + 512);
    add4(acc[0], ra0); add4(acc[1], ra1); add4(acc[2], ra2);
    add4(acc[0], rb0); add4(acc[1], rb1); add4(acc[2], rb2);
    float ea = ((ra0.x + ra0.y) + (ra0.z + ra0.w))
             + ((ra1.x + ra1.y) + (ra1.z + ra1.w))
             + ((ra2.x + ra2.y) + (ra2.z + ra2.w));
    float eb = ((rb0.x + rb0.y) + (rb0.z + rb0.w))
             + ((rb1.x + rb1.y) + (rb1.z + rb1.w))
             + ((rb2.x + rb2.y) + (rb2.z + rb2.w));
    #pragma unroll
    for (int off = 32; off; off >>= 1) {
      ea += __shfl_xor(ea, off);
      eb += __shfl_xor(eb, off);
    }
    if (lane == 0) { Mg[task * NTOK + ta] = ea; Mg[task * NTOK + tb] = eb; }
  }
  {
    const int t = tbase + wv + 24;   // tail token (i = 6)
    const float* p = lanebase + (size_t)t * CDIM;
    float4 r0 = *(const float4*)(p);
    float4 r1 = *(const float4*)(p + 256);
    float4 r2 = *(const float4*)(p + 512);
    add4(acc[0], r0); add4(acc[1], r1); add4(acc[2], r2);
    float e = ((r0.x + r0.y) + (r0.z + r0.w))
            + ((r1.x + r1.y) + (r1.z + r1.w))
            + ((r2.x + r2.y) + (r2.z + r2.w));
    #pragma unroll
    for (int off = 32; off; off >>= 1) e += __shfl_xor(e, off);
    if (lane == 0) Mg[task * NTOK + t] = e;
  }

  // combine 4 wave partials -> chunk partial column sum
  const int base = lane * 4;
  #pragma unroll
  for (int g = 0; g < 3; g++)
    *(float4*)&part[wv][base + g * 256] = acc[g];
  __syncthreads();

  #pragma unroll
  for (int q = 0; q < 3; q++) {
    const int c = tid + 256 * q;
    const float v = part[0][c] + part[1][c] + part[2][c] + part[3][c];
    colp[((size_t)task * NCHK + chunk) * CDIM + c] = v;
  }
}

// ---------------------------------------------------------------------------
// K2: per-task finalize. 512 blocks x 256 threads (4 waves).
// Phase B logic identical to the passing kernel (guards are tid<196/tid<64;
// only the min/max cross-wave combine shrinks 8->4 partials -- exact ops).
// Phase C: subset re-read, register batch-4 per wave. m = min(k,196-k) is
// typically tiny (gap-argmax of normalized normals lands at the tails), and
// the rows are L2/L3-hot from K1.
// ---------------------------------------------------------------------------
__global__ __launch_bounds__(256) void finalize_kernel(const float* __restrict__ x1,
                                                       const float* __restrict__ x2,
                                                       const float* __restrict__ colp,
                                                       const float* __restrict__ Mg,
                                                       __hip_bfloat16* __restrict__ Vb) {
  const int task = blockIdx.x;
  const int s  = task & 255;
  const int br = task >> 8;
  const float* __restrict__ feats = (br ? x2 : x1) + (size_t)s * (NTOK * CDIM);

  const int tid  = threadIdx.x;
  const int lane = tid & 63;
  const int wv   = tid >> 6;   // 0..3

  __shared__ float Msh[NTOK];
  __shared__ float Mn[NTOK];
  __shared__ float sortedv[NTOK];
  __shared__ int   rnk[NTOK];
  __shared__ int   list[NTOK];
  __shared__ float redmin[4], redmax[4];
  __shared__ int   kSh;
  __shared__ int   cntSh;
  __shared__ float partT[4][CDIM];   // 12 KB

  if (tid < NTOK) Msh[tid] = Mg[task * NTOK + tid];
  if (tid == 0) cntSh = 0;
  __syncthreads();

  // ---------------- Phase B ----------------
  float vmn = (tid < NTOK) ? Msh[tid] :  1e30f;
  float vmx = (tid < NTOK) ? Msh[tid] : -1e30f;
  #pragma unroll
  for (int off = 32; off; off >>= 1) {
    vmn = fminf(vmn, __shfl_xor(vmn, off));
    vmx = fmaxf(vmx, __shfl_xor(vmx, off));
  }
  if (lane == 0) { redmin[wv] = vmn; redmax[wv] = vmx; }
  __syncthreads();
  float mn = redmin[0], mx = redmax[0];
  #pragma unroll
  for (int i = 1; i < 4; i++) { mn = fminf(mn, redmin[i]); mx = fmaxf(mx, redmax[i]); }
  const float rng = mx - mn;
  if (tid < NTOK) Mn[tid] = (Msh[tid] - mn) / rng;   // exact IEEE div, like ref
  __syncthreads();

  if (tid < NTOK) {
    const float mv = Mn[tid];
    int r = 0;
    for (int u = 0; u < NTOK; u++) {
      const float o = Mn[u];
      r += (o < mv) || (o == mv && u < tid);   // stable argsort tie-break
    }
    sortedv[r] = mv;
    rnk[tid] = r;
  }
  __syncthreads();

  if (tid < 64) {
    float bd = -1.0f; int bj = NTOK;
    for (int j = lane; j < NTOK - 1; j += 64) {
      const float sj = sortedv[j];
      const float d = (sj == 0.0f) ? 0.0f : (sortedv[j + 1] - sj);
      if (d > bd || (d == bd && j < bj)) { bd = d; bj = j; }
    }
    #pragma unroll
    for (int off = 32; off; off >>= 1) {
      const float od = __shfl_xor(bd, off);
      const int   oj = __shfl_xor(bj, off);
      if (od > bd || (od == bd && oj < bj)) { bd = od; bj = oj; }
    }
    if (lane == 0) kSh = bj;   // first-occurrence argmax
  }
  __syncthreads();

  const int k = kSh;
  const bool takeFg = (k <= NTOK / 2);

  // compact the smaller set's token indices (order irrelevant for the sum)
  if (tid < NTOK) {
    const int r = rnk[tid];
    const bool inSet = takeFg ? (r < k) : (r >= k);
    if (inSet) { int p = atomicAdd(&cntSh, 1); list[p] = tid; }
  }
  __syncthreads();
  const int m = cntSh;

  // ---------------- Phase C (batch-4 register loads over list) ----------------
  float4 tacc[3];
  #pragma unroll
  for (int g = 0; g < 3; g++) tacc[g] = make_float4(0.f, 0.f, 0.f, 0.f);

  const float* lanebase = feats + lane * 4;
  for (int i0 = wv * 4; i0 < m; i0 += 16) {
    const int nb = m - i0;   // wave-uniform; >=1
    float4 r[4][3];
    #pragma unroll
    for (int j = 0; j < 4; j++) {
      if (j < nb) {
        const int t = list[i0 + j];
        const float* p = lanebase + (size_t)t * CDIM;
        #pragma unroll
        for (int g = 0; g < 3; g++) r[j][g] = *(const float4*)(p + g * 256);
      }
    }
    #pragma unroll
    for (int j = 0; j < 4; j++) {
      if (j < nb) {
        #pragma unroll
        for (int g = 0; g < 3; g++) add4(tacc[g], r[j][g]);
      }
    }
  }

  const int base = lane * 4;
  #pragma unroll
  for (int g = 0; g < 3; g++)
    *(float4*)&partT[wv][base + g * 256] = tacc[g];
  __syncthreads();

  const float fgc = (float)(k > 1 ? k : 1);
  const float bgc = (float)((NTOK - k) > 1 ? (NTOK - k) : 1);
  const size_t rowFg = (size_t)(2 * br + 1) * BSAMP + s;
  const size_t rowBg = (size_t)(2 * br    ) * BSAMP + s;
  for (int c = tid; c < CDIM; c += 256) {
    float T = partT[0][c] + partT[1][c] + partT[2][c] + partT[3][c];
    float S = 0.0f;
    #pragma unroll
    for (int ch = 0; ch < NCHK; ch++)
      S += colp[((size_t)task * NCHK + ch) * CDIM + c];
    float fg, bg;
    if (takeFg) { fg = T;     bg = S - T; }
    else        { bg = T;     fg = S - T; }
    Vb[rowFg * CDIM + c] = __float2bfloat16(fg / fgc);
    Vb[rowBg * CDIM + c] = __float2bfloat16(bg / bgc);
  }
}

// W [768][701] fp32 -> WT [704][768] bf16 (rows 701..703 zero-padded).
__global__ __launch_bounds__(256) void wt_kernel(const float* __restrict__ W,
                                                 __hip_bfloat16* __restrict__ WT) {
  __shared__ float tile[32][33];
  const int c0 = blockIdx.x * 32;   // class cols of W
  const int k0 = blockIdx.y * 32;   // k rows of W
  const int tx = threadIdx.x & 31;
  const int ty = threadIdx.x >> 5;  // 0..7
  #pragma unroll
  for (int i = 0; i < 4; i++) {
    const int kr = ty + i * 8;      // 0..31
    const int c = c0 + tx;
    tile[kr][tx] = (c < NCLS) ? W[(size_t)(k0 + kr) * NCLS + c] : 0.0f;
  }
  __syncthreads();
  #pragma unroll
  for (int i = 0; i < 4; i++) {
    const int cr = ty + i * 8;      // class row within tile
    const int cls = c0 + cr;        // < 704 always
    WT[(size_t)cls * CDIM + k0 + tx] = __float2bfloat16(tile[tx][cr]);
  }
}

// Vb [1024][768] bf16 (row-major, K contiguous) x WT [704][768] bf16
// -> out [1024][701] fp32 (+bias). One 16x16 tile per wave via
// mfma_f32_16x16x32_bf16; K-loop fully unrolled (24 MFMA).
// A-frag: lane holds A[m=lane&15][k=(lane>>4)*8 + j]  (16B contiguous)
// B-frag: lane holds B[k=(lane>>4)*8 + j][n=lane&15]  (= WT row, contiguous)
// C/D  : col=lane&15, row=(lane>>4)*4+reg   [m89/m91-verified]
__global__ __launch_bounds__(256) void mfma_gemm(const __hip_bfloat16* __restrict__ Vb,
                                                 const __hip_bfloat16* __restrict__ WT,
                                                 const float* __restrict__ bias,
                                                 float* __restrict__ out) {
  const int w = blockIdx.x * 4 + (threadIdx.x >> 6);   // 0..2815
  const int lane = threadIdx.x & 63;
  const int tr = w / (NCLSP / 16);   // 0..63
  const int tc = w % (NCLSP / 16);   // 0..43
  const int m0 = tr * 16;
  const int n0 = tc * 16;
  const int ko = (lane >> 4) * 8;

  const short* aptr = (const short*)Vb + (size_t)(m0 + (lane & 15)) * CDIM + ko;
  const short* bptr = (const short*)WT + (size_t)(n0 + (lane & 15)) * CDIM + ko;

  f32x4 acc = {0.f, 0.f, 0.f, 0.f};
  #pragma unroll
  for (int k0 = 0; k0 < CDIM; k0 += 32) {
    const bf16x8 af = *(const bf16x8*)(aptr + k0);
    const bf16x8 bf = *(const bf16x8*)(bptr + k0);
    acc = __builtin_amdgcn_mfma_f32_16x16x32_bf16(af, bf, acc, 0, 0, 0);
  }

  const int crow = m0 + (lane >> 4) * 4;
  const int ccol = n0 + (lane & 15);
  if (ccol < NCLS) {
    const float bv = bias[ccol];
    #pragma unroll
    for (int r = 0; r < 4; r++)
      out[(size_t)(crow + r) * NCLS + ccol] = acc[r] + bv;
  }
}

extern "C" void kernel_launch(void* const* d_in, const int* in_sizes, int n_in,
                              void* d_out, int out_size, void* d_ws, size_t ws_size,
                              hipStream_t stream) {
  const float* x1 = (const float*)d_in[0];
  const float* x2 = (const float*)d_in[1];
  const float* W  = (const float*)d_in[2];
  const float* b  = (const float*)d_in[3];
  float* out = (float*)d_out;

  // workspace layout
  const size_t VB_BYTES   = (size_t)4 * BSAMP * CDIM * 2;          // 1.5 MB
  const size_t WT_BYTES   = (size_t)NCLSP * CDIM * 2;              // 1.08 MB
  const size_t COLP_BYTES = (size_t)TASKS * NCHK * CDIM * 4;       // 10.5 MB
  __hip_bfloat16* Vb = (__hip_bfloat16*)d_ws;
  __hip_bfloat16* WT = (__hip_bfloat16*)((char*)d_ws + VB_BYTES);
  float* colp = (float*)((char*)d_ws + VB_BYTES + WT_BYTES);
  float* Mg   = (float*)((char*)d_ws + VB_BYTES + WT_BYTES + COLP_BYTES); // 0.4 MB

  colsum_kernel<<<TASKS * NCHK, 256, 0, stream>>>(x1, x2, colp, Mg);
  finalize_kernel<<<TASKS, 256, 0, stream>>>(x1, x2, colp, Mg, Vb);
  wt_kernel<<<dim3(22, 24), 256, 0, stream>>>(W, WT);
  mfma_gemm<<<704, 256, 0, stream>>>(Vb, WT, b, out);
}

// Round 5
// 331.578 us; speedup vs baseline: 1.0611x; 1.0611x over previous
//
#include <hip/hip_runtime.h>
#include <hip/hip_bf16.h>

#define NTOK 196
#define CDIM 768
#define BSAMP 256
#define TASKS 512
#define NCLS 701
#define NCLSP 704
#define NCHK 7      // chunks per task
#define CHTOK 28    // tokens per chunk (7 tokens per wave x 4 waves)

typedef __attribute__((ext_vector_type(8))) short bf16x8;
typedef __attribute__((ext_vector_type(4))) float f32x4;

__device__ __forceinline__ void add4(float4& a, const float4& b) {
  a.x += b.x; a.y += b.y; a.z += b.z; a.w += b.w;
}

// Non-temporal 16B load: nt bit = no-allocate/evict-first in L2/L3.
// R0-R4 all pinned at ~2.5-2.7 TB/s delivery with ~half the stream served
// by L3 (FETCH 150MB vs 301MB consumed) -- theory: the L3-hit path is in
// series on the same fabric, capping combined delivery. nt streams all
// bytes from HBM; if the HBM read path sustains >2.7 TB/s this is a win.
__device__ __forceinline__ f32x4 ntload(const float* p) {
  return __builtin_nontemporal_load((const f32x4*)p);
}

// ---------------------------------------------------------------------------
// K1: streaming column-sum + energy kernel. 3584 blocks x 256 thr (R4
// structure, measured 113us @ 72% occupancy). R5 delta: loads are
// non-temporal; arithmetic (lane mapping, add tree, butterfly) bit-identical.
// ---------------------------------------------------------------------------
__global__ __launch_bounds__(256, 8) void colsum_kernel(const float* __restrict__ x1,
                                                        const float* __restrict__ x2,
                                                        float* __restrict__ colp,
                                                        float* __restrict__ Mg) {
  const int blk   = blockIdx.x;        // 0..3583
  const int task  = blk / NCHK;        // 0..511
  const int chunk = blk % NCHK;        // 0..6
  const int s  = task & 255;
  const int br = task >> 8;
  const float* __restrict__ feats = (br ? x2 : x1) + (size_t)s * (NTOK * CDIM);

  const int tid  = threadIdx.x;
  const int lane = tid & 63;
  const int wv   = tid >> 6;   // 0..3

  __shared__ float part[4][CDIM];   // 12 KB

  f32x4 acc0 = {0.f, 0.f, 0.f, 0.f};
  f32x4 acc1 = {0.f, 0.f, 0.f, 0.f};
  f32x4 acc2 = {0.f, 0.f, 0.f, 0.f};

  const float* lanebase = feats + lane * 4;
  const int tbase = chunk * CHTOK;

  // 3 pairs + 1 tail = 7 tokens per wave; pairs give 6 nt loads in flight
  // and two independent butterfly chains.
  #pragma unroll 1
  for (int i = 0; i < 6; i += 2) {
    const int ta = tbase + wv + 4 * i;
    const int tb = ta + 4;
    const float* pa = lanebase + (size_t)ta * CDIM;
    const float* pb = lanebase + (size_t)tb * CDIM;
    f32x4 ra0 = ntload(pa);
    f32x4 ra1 = ntload(pa + 256);
    f32x4 ra2 = ntload(pa + 512);
    f32x4 rb0 = ntload(pb);
    f32x4 rb1 = ntload(pb + 256);
    f32x4 rb2 = ntload(pb + 512);
    acc0 += ra0; acc1 += ra1; acc2 += ra2;
    acc0 += rb0; acc1 += rb1; acc2 += rb2;
    float ea = ((ra0[0] + ra0[1]) + (ra0[2] + ra0[3]))
             + ((ra1[0] + ra1[1]) + (ra1[2] + ra1[3]))
             + ((ra2[0] + ra2[1]) + (ra2[2] + ra2[3]));
    float eb = ((rb0[0] + rb0[1]) + (rb0[2] + rb0[3]))
             + ((rb1[0] + rb1[1]) + (rb1[2] + rb1[3]))
             + ((rb2[0] + rb2[1]) + (rb2[2] + rb2[3]));
    #pragma unroll
    for (int off = 32; off; off >>= 1) {
      ea += __shfl_xor(ea, off);
      eb += __shfl_xor(eb, off);
    }
    if (lane == 0) { Mg[task * NTOK + ta] = ea; Mg[task * NTOK + tb] = eb; }
  }
  {
    const int t = tbase + wv + 24;   // tail token (i = 6)
    const float* p = lanebase + (size_t)t * CDIM;
    f32x4 r0 = ntload(p);
    f32x4 r1 = ntload(p + 256);
    f32x4 r2 = ntload(p + 512);
    acc0 += r0; acc1 += r1; acc2 += r2;
    float e = ((r0[0] + r0[1]) + (r0[2] + r0[3]))
            + ((r1[0] + r1[1]) + (r1[2] + r1[3]))
            + ((r2[0] + r2[1]) + (r2[2] + r2[3]));
    #pragma unroll
    for (int off = 32; off; off >>= 1) e += __shfl_xor(e, off);
    if (lane == 0) Mg[task * NTOK + t] = e;
  }

  // combine 4 wave partials -> chunk partial column sum
  const int base = lane * 4;
  *(f32x4*)&part[wv][base]       = acc0;
  *(f32x4*)&part[wv][base + 256] = acc1;
  *(f32x4*)&part[wv][base + 512] = acc2;
  __syncthreads();

  #pragma unroll
  for (int q = 0; q < 3; q++) {
    const int c = tid + 256 * q;
    const float v = part[0][c] + part[1][c] + part[2][c] + part[3][c];
    colp[((size_t)task * NCHK + chunk) * CDIM + c] = v;
  }
}

// ---------------------------------------------------------------------------
// K2: per-task finalize. 512 blocks x 256 threads (4 waves). Unchanged from
// R4 (Phase B logic exact; Phase C subset re-read -- m is typically 1..5
// tokens so losing L3 warmth from K1's nt loads costs only a few MB).
// ---------------------------------------------------------------------------
__global__ __launch_bounds__(256) void finalize_kernel(const float* __restrict__ x1,
                                                       const float* __restrict__ x2,
                                                       const float* __restrict__ colp,
                                                       const float* __restrict__ Mg,
                                                       __hip_bfloat16* __restrict__ Vb) {
  const int task = blockIdx.x;
  const int s  = task & 255;
  const int br = task >> 8;
  const float* __restrict__ feats = (br ? x2 : x1) + (size_t)s * (NTOK * CDIM);

  const int tid  = threadIdx.x;
  const int lane = tid & 63;
  const int wv   = tid >> 6;   // 0..3

  __shared__ float Msh[NTOK];
  __shared__ float Mn[NTOK];
  __shared__ float sortedv[NTOK];
  __shared__ int   rnk[NTOK];
  __shared__ int   list[NTOK];
  __shared__ float redmin[4], redmax[4];
  __shared__ int   kSh;
  __shared__ int   cntSh;
  __shared__ float partT[4][CDIM];   // 12 KB

  if (tid < NTOK) Msh[tid] = Mg[task * NTOK + tid];
  if (tid == 0) cntSh = 0;
  __syncthreads();

  // ---------------- Phase B ----------------
  float vmn = (tid < NTOK) ? Msh[tid] :  1e30f;
  float vmx = (tid < NTOK) ? Msh[tid] : -1e30f;
  #pragma unroll
  for (int off = 32; off; off >>= 1) {
    vmn = fminf(vmn, __shfl_xor(vmn, off));
    vmx = fmaxf(vmx, __shfl_xor(vmx, off));
  }
  if (lane == 0) { redmin[wv] = vmn; redmax[wv] = vmx; }
  __syncthreads();
  float mn = redmin[0], mx = redmax[0];
  #pragma unroll
  for (int i = 1; i < 4; i++) { mn = fminf(mn, redmin[i]); mx = fmaxf(mx, redmax[i]); }
  const float rng = mx - mn;
  if (tid < NTOK) Mn[tid] = (Msh[tid] - mn) / rng;   // exact IEEE div, like ref
  __syncthreads();

  if (tid < NTOK) {
    const float mv = Mn[tid];
    int r = 0;
    for (int u = 0; u < NTOK; u++) {
      const float o = Mn[u];
      r += (o < mv) || (o == mv && u < tid);   // stable argsort tie-break
    }
    sortedv[r] = mv;
    rnk[tid] = r;
  }
  __syncthreads();

  if (tid < 64) {
    float bd = -1.0f; int bj = NTOK;
    for (int j = lane; j < NTOK - 1; j += 64) {
      const float sj = sortedv[j];
      const float d = (sj == 0.0f) ? 0.0f : (sortedv[j + 1] - sj);
      if (d > bd || (d == bd && j < bj)) { bd = d; bj = j; }
    }
    #pragma unroll
    for (int off = 32; off; off >>= 1) {
      const float od = __shfl_xor(bd, off);
      const int   oj = __shfl_xor(bj, off);
      if (od > bd || (od == bd && oj < bj)) { bd = od; bj = oj; }
    }
    if (lane == 0) kSh = bj;   // first-occurrence argmax
  }
  __syncthreads();

  const int k = kSh;
  const bool takeFg = (k <= NTOK / 2);

  // compact the smaller set's token indices (order irrelevant for the sum)
  if (tid < NTOK) {
    const int r = rnk[tid];
    const bool inSet = takeFg ? (r < k) : (r >= k);
    if (inSet) { int p = atomicAdd(&cntSh, 1); list[p] = tid; }
  }
  __syncthreads();
  const int m = cntSh;

  // ---------------- Phase C (batch-4 register loads over list) ----------------
  float4 tacc[3];
  #pragma unroll
  for (int g = 0; g < 3; g++) tacc[g] = make_float4(0.f, 0.f, 0.f, 0.f);

  const float* lanebase = feats + lane * 4;
  for (int i0 = wv * 4; i0 < m; i0 += 16) {
    const int nb = m - i0;   // wave-uniform; >=1
    float4 r[4][3];
    #pragma unroll
    for (int j = 0; j < 4; j++) {
      if (j < nb) {
        const int t = list[i0 + j];
        const float* p = lanebase + (size_t)t * CDIM;
        #pragma unroll
        for (int g = 0; g < 3; g++) r[j][g] = *(const float4*)(p + g * 256);
      }
    }
    #pragma unroll
    for (int j = 0; j < 4; j++) {
      if (j < nb) {
        #pragma unroll
        for (int g = 0; g < 3; g++) add4(tacc[g], r[j][g]);
      }
    }
  }

  const int base = lane * 4;
  #pragma unroll
  for (int g = 0; g < 3; g++)
    *(float4*)&partT[wv][base + g * 256] = tacc[g];
  __syncthreads();

  const float fgc = (float)(k > 1 ? k : 1);
  const float bgc = (float)((NTOK - k) > 1 ? (NTOK - k) : 1);
  const size_t rowFg = (size_t)(2 * br + 1) * BSAMP + s;
  const size_t rowBg = (size_t)(2 * br    ) * BSAMP + s;
  for (int c = tid; c < CDIM; c += 256) {
    float T = partT[0][c] + partT[1][c] + partT[2][c] + partT[3][c];
    float S = 0.0f;
    #pragma unroll
    for (int ch = 0; ch < NCHK; ch++)
      S += colp[((size_t)task * NCHK + ch) * CDIM + c];
    float fg, bg;
    if (takeFg) { fg = T;     bg = S - T; }
    else        { bg = T;     fg = S - T; }
    Vb[rowFg * CDIM + c] = __float2bfloat16(fg / fgc);
    Vb[rowBg * CDIM + c] = __float2bfloat16(bg / bgc);
  }
}

// W [768][701] fp32 -> WT [704][768] bf16 (rows 701..703 zero-padded).
__global__ __launch_bounds__(256) void wt_kernel(const float* __restrict__ W,
                                                 __hip_bfloat16* __restrict__ WT) {
  __shared__ float tile[32][33];
  const int c0 = blockIdx.x * 32;   // class cols of W
  const int k0 = blockIdx.y * 32;   // k rows of W
  const int tx = threadIdx.x & 31;
  const int ty = threadIdx.x >> 5;  // 0..7
  #pragma unroll
  for (int i = 0; i < 4; i++) {
    const int kr = ty + i * 8;      // 0..31
    const int c = c0 + tx;
    tile[kr][tx] = (c < NCLS) ? W[(size_t)(k0 + kr) * NCLS + c] : 0.0f;
  }
  __syncthreads();
  #pragma unroll
  for (int i = 0; i < 4; i++) {
    const int cr = ty + i * 8;      // class row within tile
    const int cls = c0 + cr;        // < 704 always
    WT[(size_t)cls * CDIM + k0 + tx] = __float2bfloat16(tile[tx][cr]);
  }
}

// Vb [1024][768] bf16 x WT [704][768] bf16 -> out [1024][701] fp32 (+bias).
// One 16x16 tile per wave via mfma_f32_16x16x32_bf16; K fully unrolled.
// C/D: col=lane&15, row=(lane>>4)*4+reg   [m89/m91-verified]
__global__ __launch_bounds__(256) void mfma_gemm(const __hip_bfloat16* __restrict__ Vb,
                                                 const __hip_bfloat16* __restrict__ WT,
                                                 const float* __restrict__ bias,
                                                 float* __restrict__ out) {
  const int w = blockIdx.x * 4 + (threadIdx.x >> 6);   // 0..2815
  const int lane = threadIdx.x & 63;
  const int tr = w / (NCLSP / 16);   // 0..63
  const int tc = w % (NCLSP / 16);   // 0..43
  const int m0 = tr * 16;
  const int n0 = tc * 16;
  const int ko = (lane >> 4) * 8;

  const short* aptr = (const short*)Vb + (size_t)(m0 + (lane & 15)) * CDIM + ko;
  const short* bptr = (const short*)WT + (size_t)(n0 + (lane & 15)) * CDIM + ko;

  f32x4 acc = {0.f, 0.f, 0.f, 0.f};
  #pragma unroll
  for (int k0 = 0; k0 < CDIM; k0 += 32) {
    const bf16x8 af = *(const bf16x8*)(aptr + k0);
    const bf16x8 bf = *(const bf16x8*)(bptr + k0);
    acc = __builtin_amdgcn_mfma_f32_16x16x32_bf16(af, bf, acc, 0, 0, 0);
  }

  const int crow = m0 + (lane >> 4) * 4;
  const int ccol = n0 + (lane & 15);
  if (ccol < NCLS) {
    const float bv = bias[ccol];
    #pragma unroll
    for (int r = 0; r < 4; r++)
      out[(size_t)(crow + r) * NCLS + ccol] = acc[r] + bv;
  }
}

extern "C" void kernel_launch(void* const* d_in, const int* in_sizes, int n_in,
                              void* d_out, int out_size, void* d_ws, size_t ws_size,
                              hipStream_t stream) {
  const float* x1 = (const float*)d_in[0];
  const float* x2 = (const float*)d_in[1];
  const float* W  = (const float*)d_in[2];
  const float* b  = (const float*)d_in[3];
  float* out = (float*)d_out;

  // workspace layout
  const size_t VB_BYTES   = (size_t)4 * BSAMP * CDIM * 2;          // 1.5 MB
  const size_t WT_BYTES   = (size_t)NCLSP * CDIM * 2;              // 1.08 MB
  const size_t COLP_BYTES = (size_t)TASKS * NCHK * CDIM * 4;       // 10.5 MB
  __hip_bfloat16* Vb = (__hip_bfloat16*)d_ws;
  __hip_bfloat16* WT = (__hip_bfloat16*)((char*)d_ws + VB_BYTES);
  float* colp = (float*)((char*)d_ws + VB_BYTES + WT_BYTES);
  float* Mg   = (float*)((char*)d_ws + VB_BYTES + WT_BYTES + COLP_BYTES); // 0.4 MB

  colsum_kernel<<<TASKS * NCHK, 256, 0, stream>>>(x1, x2, colp, Mg);
  finalize_kernel<<<TASKS, 256, 0, stream>>>(x1, x2, colp, Mg, Vb);
  wt_kernel<<<dim3(22, 24), 256, 0, stream>>>(W, WT);
  mfma_gemm<<<704, 256, 0, stream>>>(Vb, WT, b, out);
}